// Round 13
// baseline (133.208 us; speedup 1.0000x reference)
//
#include <hip/hip_runtime.h>
#include <hip/hip_bf16.h>
#include <math.h>

#define NCAP 10
#define DCAP 16
#define DIN  128
#define NPOS 4096
#define NB   64

typedef short short8 __attribute__((ext_vector_type(8)));
typedef float floatx4 __attribute__((ext_vector_type(4)));

__device__ inline float bflo(unsigned v) { return __uint_as_float(v << 16); }
__device__ inline float bfhi(unsigned v) { return __uint_as_float(v & 0xFFFF0000u); }
__device__ inline unsigned short f2bf(float f) {           // round-to-nearest-even
    unsigned u = __float_as_uint(f);
    return (unsigned short)((u + 0x7FFFu + ((u >> 16) & 1u)) >> 16);
}

// ===========================================================================
// BIG PATH (ws >= 86,679,552 B)
//   regionA : @0, 2,621,440 B — first 512 KB: col-sum partial [64][16][128] f32
//             (consumed by small0); then route partials pws [64][64][160] f32
//   vbuf    : @2,621,440 (40,960 B)  f32 [64][10][16]
//   WTg     : @2,662,400 (40,960 B)  bf16 swizzled W
//   uf      : @2,703,360 (83,886,080 B) fragment-native u_hat (bf16 pairs)
//             uint2 index: ((((b*16+blk)*4+mt)*4+wv)*10 + n)*64 + l
//             lane l holds (pos = blk*256+mt*64+wv*16+(l&15),
//                           d = (l>>4)*4 + {0,1} / {2,3} in .x/.y)
// ===========================================================================

// One-time: pre-swizzle W (f32 [128][160]) -> WTg rows=out-col(n*16+d),
// 16 chunks of 8 k's, chunk kc stored at (kc ^ (row&15)).
__global__ __launch_bounds__(256) void wprep(const float* __restrict__ W,
                                             uint4* __restrict__ WTg) {
    const int cid = blockIdx.x * 256 + threadIdx.x;   // 2560 chunks
    if (cid >= 2560) return;
    const int row = cid >> 4;
    const int csn = cid & 15;
    const int kc = csn ^ (row & 15);
    unsigned p[4];
    #pragma unroll
    for (int e = 0; e < 4; ++e) {
        const float a = W[(kc * 8 + e * 2) * 160 + row];
        const float b = W[(kc * 8 + e * 2 + 1) * 160 + row];
        p[e] = (unsigned)f2bf(a) | ((unsigned)f2bf(b) << 16);
    }
    WTg[cid] = make_uint4(p[0], p[1], p[2], p[3]);
}

// u_hat via bf16 MFMA, swapped operands (A = W rows (n,d), B = u cols pos).
// C stored fragment-native from registers: no C-LDS, no K-loop barriers.
__global__ __launch_bounds__(256) void gemm_uhat(const float* __restrict__ u,
                                                 const uint4* __restrict__ WTg,
                                                 uint2* __restrict__ uf2,
                                                 float* __restrict__ partial) {
    const int b = blockIdx.x;
    const int blk = blockIdx.y;            // 16 blocks per b, 256 pos each
    const int t = threadIdx.x;
    const int l = t & 63;
    const int wv = __builtin_amdgcn_readfirstlane(t >> 6);

    __shared__ uint4 WT4[2560];            // 40960 B

    // ---- stage pre-swizzled W: coalesced, conflict-free ----
    #pragma unroll
    for (int i = 0; i < 10; ++i)
        WT4[t + i * 256] = WTg[t + i * 256];
    __syncthreads();

    float cs[4][8];
    #pragma unroll
    for (int kk = 0; kk < 4; ++kk)
        #pragma unroll
        for (int e = 0; e < 8; ++e) cs[kk][e] = 0.f;

    const short8* wt8 = (const short8*)WT4;
    const float4* u4g = (const float4*)u;

    #pragma unroll 1
    for (int mt = 0; mt < 4; ++mt) {
        // ---- B-frags (u) direct from global + convert + col-sum ----
        const size_t row = (size_t)b * NPOS + blk * 256 + mt * 64 + wv * 16 + (l & 15);
        short8 bfr[4];
        #pragma unroll
        for (int kk = 0; kk < 4; ++kk) {
            const float4 x0 = u4g[row * 32 + kk * 8 + (l >> 4) * 2];
            const float4 x1 = u4g[row * 32 + kk * 8 + (l >> 4) * 2 + 1];
            cs[kk][0] += x0.x; cs[kk][1] += x0.y; cs[kk][2] += x0.z; cs[kk][3] += x0.w;
            cs[kk][4] += x1.x; cs[kk][5] += x1.y; cs[kk][6] += x1.z; cs[kk][7] += x1.w;
            short8 a;
            a[0] = (short)f2bf(x0.x); a[1] = (short)f2bf(x0.y);
            a[2] = (short)f2bf(x0.z); a[3] = (short)f2bf(x0.w);
            a[4] = (short)f2bf(x1.x); a[5] = (short)f2bf(x1.y);
            a[6] = (short)f2bf(x1.z); a[7] = (short)f2bf(x1.w);
            bfr[kk] = a;
        }

        // ---- per n: 4 MFMA (K=128), pack, store fragment-native ----
        const size_t cell = (((size_t)(b * 16 + blk) * 4 + mt) * 4 + wv) * 10;
        #pragma unroll 2
        for (int n = 0; n < 10; ++n) {
            floatx4 a = {0.f, 0.f, 0.f, 0.f};
            #pragma unroll
            for (int kk = 0; kk < 4; ++kk) {
                const short8 wf = wt8[(n * 16 + (l & 15)) * 16 +
                                      ((kk * 4 + (l >> 4)) ^ (l & 15))];
                a = __builtin_amdgcn_mfma_f32_16x16x32_bf16(wf, bfr[kk], a, 0, 0, 0);
            }
            uint2 pk;
            pk.x = (unsigned)f2bf(a[0]) | ((unsigned)f2bf(a[1]) << 16);
            pk.y = (unsigned)f2bf(a[2]) | ((unsigned)f2bf(a[3]) << 16);
            uf2[(cell + n) * 64 + l] = pk;
        }
    }

    // ---- fold col-sums: reduce 16 pos-lanes; 4 waves via LDS ----
    __syncthreads();                       // all MFMA reads of WT4 done
    float* csbuf = (float*)WT4;
    #pragma unroll
    for (int kk = 0; kk < 4; ++kk)
        #pragma unroll
        for (int e = 0; e < 8; ++e) {
            float v = cs[kk][e];
            v += __shfl_xor(v, 1); v += __shfl_xor(v, 2);
            v += __shfl_xor(v, 4); v += __shfl_xor(v, 8);
            cs[kk][e] = v;
        }
    if ((l & 15) == 0) {
        #pragma unroll
        for (int kk = 0; kk < 4; ++kk)
            #pragma unroll
            for (int e = 0; e < 8; ++e)
                csbuf[wv * 128 + kk * 32 + (l >> 4) * 8 + e] = cs[kk][e];
    }
    __syncthreads();
    if (t < 128)
        partial[(size_t)(b * 16 + blk) * 128 + t] =
            csbuf[t] + csbuf[128 + t] + csbuf[256 + t] + csbuf[384 + t];
}

// v1 from col-sum partials: s1 = 0.1 * (sum_i u) @ W -> squash -> vbuf.
__global__ __launch_bounds__(128) void small0(const float* __restrict__ partial,
                                              const float* __restrict__ W,
                                              float* __restrict__ vbuf) {
    const int b = blockIdx.x / NCAP;
    const int n = blockIdx.x % NCAP;
    const int t = threadIdx.x;
    __shared__ float xv[DIN];
    float a = 0.f;
    #pragma unroll 4
    for (int c = 0; c < 16; ++c)
        a += partial[(size_t)(b * 16 + c) * DIN + t];
    xv[t] = a;
    __syncthreads();
    if (t < DCAP) {
        float sv = 0.f;
        for (int d = 0; d < DIN; ++d)
            sv = fmaf(xv[d], W[d * 160 + n * DCAP + t], sv);
        sv *= 0.1f;
        float nq = sv * sv;
        #pragma unroll
        for (int mm = 8; mm >= 1; mm >>= 1) nq += __shfl_xor(nq, mm, 16);
        nq += 1e-7f;
        vbuf[(size_t)(b * NCAP + n) * DCAP + t] = sv * sqrtf(nq) / (1.0f + nq);
    }
}

// Routing on fragment-native uf. Block = (b, g): g -> (blk = g>>2, mt = g&3);
// wave w = wv cell. Lane l: pos = l&15 (one position), d = (l>>4)*4 + r.
// logits: in-lane 4-fma d-partial + shfl_xor(16,32); softmax fully in-lane;
// PV in-lane; s-partial reduced over 16 pos-lanes; 4-wave LDS fold.
__global__ __launch_bounds__(256) void route_uf(const uint2* __restrict__ uf2,
                                                const float* __restrict__ vbuf,
                                                float* __restrict__ pws) {
    const int b = blockIdx.x;
    const int g = blockIdx.y;              // 64: blk*4 + mt
    const int t = threadIdx.x;
    const int l = t & 63;
    const int w = __builtin_amdgcn_readfirstlane(t >> 6);

    const size_t cell = (((size_t)(b * 16 + (g >> 2)) * 4 + (g & 3)) * 4 + w) * 10;

    float vals[10][4];
    float lg[10];
    #pragma unroll
    for (int n = 0; n < 10; ++n) {
        const uint2 q = uf2[(cell + n) * 64 + l];
        vals[n][0] = bflo(q.x); vals[n][1] = bfhi(q.x);
        vals[n][2] = bflo(q.y); vals[n][3] = bfhi(q.y);
        const float4 vq = *(const float4*)&vbuf[(size_t)(b * 10 + n) * 16 + (l >> 4) * 4];
        lg[n] = vals[n][0] * vq.x + vals[n][1] * vq.y +
                vals[n][2] * vq.z + vals[n][3] * vq.w;
    }
    // reduce the 4 d-groups -> full logits in every lane
    #pragma unroll
    for (int n = 0; n < 10; ++n) {
        lg[n] += __shfl_xor(lg[n], 16);
        lg[n] += __shfl_xor(lg[n], 32);
    }
    // softmax over n, in-lane
    float m = lg[0];
    #pragma unroll
    for (int n = 1; n < 10; ++n) m = fmaxf(m, lg[n]);
    float ssum = 0.f;
    float c[10];
    #pragma unroll
    for (int n = 0; n < 10; ++n) { c[n] = __expf(lg[n] - m); ssum += c[n]; }
    const float inv = 1.0f / ssum;

    // PV: s-partial for this lane's pos, then reduce over 16 pos-lanes
    float sp[10][4];
    #pragma unroll
    for (int n = 0; n < 10; ++n) {
        const float cn = c[n] * inv;
        #pragma unroll
        for (int r = 0; r < 4; ++r) sp[n][r] = cn * vals[n][r];
    }
    #pragma unroll
    for (int n = 0; n < 10; ++n)
        #pragma unroll
        for (int r = 0; r < 4; ++r) {
            float v = sp[n][r];
            v += __shfl_xor(v, 1); v += __shfl_xor(v, 2);
            v += __shfl_xor(v, 4); v += __shfl_xor(v, 8);
            sp[n][r] = v;
        }

    __shared__ float sm[4][160];
    if ((l & 15) == 0) {
        #pragma unroll
        for (int n = 0; n < 10; ++n)
            #pragma unroll
            for (int r = 0; r < 4; ++r)
                sm[w][n * 16 + (l >> 4) * 4 + r] = sp[n][r];
    }
    __syncthreads();
    if (t < 160)
        pws[(size_t)(b * 64 + g) * 160 + t] =
            sm[0][t] + sm[1][t] + sm[2][t] + sm[3][t];
}

// Fold 64 block-partials -> s -> squash -> v (dst = vbuf or out).
__global__ __launch_bounds__(256) void smallv(const float* __restrict__ pws,
                                              float* __restrict__ dst) {
    const int b = blockIdx.x;
    const int t = threadIdx.x;
    if (t >= 160) return;
    float a = 0.f;
    #pragma unroll 8
    for (int c = 0; c < 64; ++c)
        a += pws[(size_t)(b * 64 + c) * 160 + t];
    float nq = a * a;
    #pragma unroll
    for (int mm = 8; mm >= 1; mm >>= 1) nq += __shfl_xor(nq, mm, 16);
    nq += 1e-7f;
    dst[(size_t)b * 160 + t] = a * sqrtf(nq) / (1.0f + nq);
}

// ===========================================================================
// FALLBACK PATH (R7, verified): f32 routing against w = W @ v.
// ===========================================================================

__global__ __launch_bounds__(256) void caps_sum(const float* __restrict__ u,
                                                float* __restrict__ partial) {
    const int b = blockIdx.x;
    const int chunk = blockIdx.y;
    const int t = threadIdx.x;
    const int v4 = t & 31;
    const int prow = t >> 5;
    const float4* up = (const float4*)u;
    const size_t posbase = (size_t)b * NPOS + chunk * 256;
    float4 acc = make_float4(0.f, 0.f, 0.f, 0.f);
    #pragma unroll 8
    for (int j = 0; j < 32; ++j) {
        float4 x = up[(posbase + prow + j * 8) * 32 + v4];
        acc.x += x.x; acc.y += x.y; acc.z += x.z; acc.w += x.w;
    }
    __shared__ float4 red[8][32];
    red[prow][v4] = acc;
    __syncthreads();
    if (t < 32) {
        float4 s = red[0][t];
        #pragma unroll
        for (int r = 1; r < 8; ++r) {
            s.x += red[r][t].x; s.y += red[r][t].y;
            s.z += red[r][t].z; s.w += red[r][t].w;
        }
        ((float4*)partial)[((size_t)b * 16 + chunk) * 32 + t] = s;
    }
}

template <int MODE>
__global__ __launch_bounds__(128) void caps_small(const float* __restrict__ src,
                                                  const float* __restrict__ W,
                                                  float* __restrict__ dst) {
    const int b = blockIdx.x / NCAP;
    const int n = blockIdx.x % NCAP;
    const int t = threadIdx.x;
    __shared__ float xv[DIN];
    __shared__ float vv[DCAP];
    float a = 0.f;
    if (MODE == 0) {
        #pragma unroll 4
        for (int c = 0; c < 16; ++c) a += src[(size_t)(b * 16 + c) * DIN + t];
    } else {
        #pragma unroll 4
        for (int c = 0; c < 16; ++c) a += src[((size_t)(b * 16 + c) * NCAP + n) * DIN + t];
    }
    xv[t] = a;
    __syncthreads();
    if (t < DCAP) {
        float sv = 0.f;
        for (int d = 0; d < DIN; ++d) sv = fmaf(xv[d], W[d * 160 + n * DCAP + t], sv);
        if (MODE == 0) sv *= 0.1f;
        float nq = sv * sv;
        #pragma unroll
        for (int mm = 8; mm >= 1; mm >>= 1) nq += __shfl_xor(nq, mm, 16);
        nq += 1e-7f;
        const float v = sv * sqrtf(nq) / (1.0f + nq);
        if (MODE == 2) dst[(size_t)(b * NCAP + n) * DCAP + t] = v;
        else vv[t] = v;
    }
    if (MODE != 2) {
        __syncthreads();
        float wd = 0.f;
        #pragma unroll
        for (int dd = 0; dd < DCAP; ++dd)
            wd = fmaf(W[t * 160 + n * DCAP + dd], vv[dd], wd);
        dst[(size_t)(b * NCAP + n) * DIN + t] = wd;
    }
}

__global__ __launch_bounds__(256, 3) void caps_route(const float* __restrict__ u,
                                                     const float* __restrict__ wsrc,
                                                     float* __restrict__ pdst) {
    const int b = blockIdx.x;
    const int tile = blockIdx.y;
    const int t = threadIdx.x;
    const int lane = t & 63;
    const int wv = __builtin_amdgcn_readfirstlane(t >> 6);
    __shared__ float4 tl4[64 * 32];
    __shared__ float lgp[4][64][11];
    float* tlf = (float*)tl4;
    const float4* wq4 = (const float4*)(wsrc + (size_t)b * (NCAP * DIN));
    float acc0[NCAP], acc1[NCAP];
    #pragma unroll
    for (int n = 0; n < NCAP; ++n) { acc0[n] = 0.f; acc1[n] = 0.f; }
    for (int s = 0; s < 4; ++s) {
        __syncthreads();
        const float4* src4 = (const float4*)u + ((size_t)b * NPOS + tile * 256 + s * 64) * 32;
        #pragma unroll
        for (int i = 0; i < 8; ++i) {
            const int q = t + i * 256;
            const int r = q >> 5, c = q & 31;
            tl4[r * 32 + (c ^ (r & 7))] = src4[q];
        }
        __syncthreads();
        float lg[NCAP];
        #pragma unroll
        for (int n = 0; n < NCAP; ++n) lg[n] = 0.f;
        #pragma unroll
        for (int j = 0; j < 8; ++j) {
            const float4 u4 = tl4[lane * 32 + wv * 8 + (j ^ (lane & 7))];
            #pragma unroll
            for (int n = 0; n < NCAP; ++n) {
                const float4 w4 = wq4[n * 32 + wv * 8 + j];
                lg[n] = fmaf(u4.x, w4.x, fmaf(u4.y, w4.y,
                        fmaf(u4.z, w4.z, fmaf(u4.w, w4.w, lg[n]))));
            }
        }
        #pragma unroll
        for (int n = 0; n < NCAP; ++n) lgp[wv][lane][n] = lg[n];
        __syncthreads();
        float c[NCAP];
        float m = -1e30f;
        #pragma unroll
        for (int n = 0; n < NCAP; ++n) {
            c[n] = lgp[0][lane][n] + lgp[1][lane][n] + lgp[2][lane][n] + lgp[3][lane][n];
            m = fmaxf(m, c[n]);
        }
        float ssum = 0.f;
        #pragma unroll
        for (int n = 0; n < NCAP; ++n) { c[n] = __expf(c[n] - m); ssum += c[n]; }
        const float inv = 1.0f / ssum;
        #pragma unroll
        for (int n = 0; n < NCAP; ++n) c[n] *= inv;
        const int col0 = lane >> 2, word = lane & 3;
        #pragma unroll
        for (int i = 0; i < 16; ++i) {
            const int p = wv * 16 + i;
            const int ca = col0 ^ (p & 7);
            const float u0 = tlf[(p * 32 + ca) * 4 + word];
            const float u1 = tlf[(p * 32 + ca + 16) * 4 + word];
            #pragma unroll
            for (int n = 0; n < NCAP; ++n) {
                const float cp = __int_as_float(
                    __builtin_amdgcn_readlane(__float_as_int(c[n]), p));
                acc0[n] = fmaf(cp, u0, acc0[n]);
                acc1[n] = fmaf(cp, u1, acc1[n]);
            }
        }
    }
    __syncthreads();
    float* red = tlf;
    #pragma unroll
    for (int n = 0; n < NCAP; ++n) {
        red[(wv * NCAP + n) * DIN + lane]      = acc0[n];
        red[(wv * NCAP + n) * DIN + lane + 64] = acc1[n];
    }
    __syncthreads();
    float* pb = pdst + (size_t)(b * 16 + tile) * (NCAP * DIN);
    for (int k = t; k < NCAP * DIN; k += 256)
        pb[k] = red[k] + red[1280 + k] + red[2560 + k] + red[3840 + k];
}

extern "C" void kernel_launch(void* const* d_in, const int* in_sizes, int n_in,
                              void* d_out, int out_size, void* d_ws, size_t ws_size,
                              hipStream_t stream) {
    const float* u = (const float*)d_in[0];   // [64][4096][128]
    const float* W = (const float*)d_in[1];   // [128][160]
    float* out = (float*)d_out;               // [64][10][16]
    char* wsb = (char*)d_ws;

    if (ws_size >= 86679552ull) {
        float* partial = (float*)wsb;                       // 512 KB (region A)
        float* pws     = (float*)wsb;                       // 2.62 MB (region A, after small0)
        float* vbuf    = (float*)(wsb + 2621440);           // 40 KB
        uint4* WTg     = (uint4*)(wsb + 2662400);           // 40 KB
        uint2* uf2     = (uint2*)(wsb + 2703360);           // 83.9 MB

        wprep<<<10, 256, 0, stream>>>(W, WTg);
        gemm_uhat<<<dim3(NB, 16), 256, 0, stream>>>(u, WTg, uf2, partial);
        small0<<<NB * NCAP, 128, 0, stream>>>(partial, W, vbuf);       // v1
        route_uf<<<dim3(NB, 64), 256, 0, stream>>>(uf2, vbuf, pws);    // iter 2
        smallv<<<NB, 256, 0, stream>>>(pws, vbuf);                     // v2
        route_uf<<<dim3(NB, 64), 256, 0, stream>>>(uf2, vbuf, pws);    // iter 3
        smallv<<<NB, 256, 0, stream>>>(pws, out);                      // v3 -> out
    } else {
        float* partial = (float*)wsb;
        float* wbuf    = (float*)wsb + 131072;
        float* pws32   = (float*)wsb + 212992;
        caps_sum<<<dim3(NB, 16), 256, 0, stream>>>(u, partial);
        caps_small<0><<<NB * NCAP, 128, 0, stream>>>(partial, W, wbuf);
        caps_route<<<dim3(NB, 16), 256, 0, stream>>>(u, wbuf, pws32);
        caps_small<1><<<NB * NCAP, 128, 0, stream>>>(pws32, W, wbuf);
        caps_route<<<dim3(NB, 16), 256, 0, stream>>>(u, wbuf, pws32);
        caps_small<2><<<NB * NCAP, 128, 0, stream>>>(pws32, W, out);
    }
}

// Round 14
// 115.456 us; speedup vs baseline: 1.1538x; 1.1538x over previous
//
#include <hip/hip_runtime.h>
#include <hip/hip_bf16.h>
#include <math.h>

#define NCAP 10
#define DCAP 16
#define DIN  128
#define NPOS 4096
#define NB   64

typedef short short8 __attribute__((ext_vector_type(8)));
typedef float floatx4 __attribute__((ext_vector_type(4)));

__device__ inline float bflo(unsigned v) { return __uint_as_float(v << 16); }
__device__ inline float bfhi(unsigned v) { return __uint_as_float(v & 0xFFFF0000u); }
__device__ inline unsigned short f2bf(float f) {           // round-to-nearest-even
    unsigned u = __float_as_uint(f);
    return (unsigned short)((u + 0x7FFFu + ((u >> 16) & 1u)) >> 16);
}
__device__ inline float bf2f(unsigned short h) { return __uint_as_float(((unsigned)h) << 16); }

// ===========================================================================
// BIG PATH (ws >= 86,679,552 B; uses 86,589,440)
//   regionA : @0, 2,621,440 B — first 1 MB: col-sum partial [64][32][128] f32
//             (consumed by small0); then route partials pws [64][64][160] f32
//   vbuf    : @2,621,440 (40,960 B)  f32 [64][10][16]
//   WTg     : @2,662,400 (40,960 B)  bf16 swizzled W [160 rows][16 chunks]
//   uf      : @2,703,360 (83,886,080 B) fragment-native u_hat (bf16 pairs)
//             uint2 index: ((b*64 + g)*4 + wv)*10 + n)*64 + l  where
//             g in [0,64) covers pos [g*64,(g+1)*64);
//             lane l: pos = g*64 + wv*16 + (l&15), d = (l>>4)*4 + {0..3}
// ===========================================================================

// One-time: pre-swizzle W (f32 [128][160]) -> WTg rows=out-col(n*16+d),
// 16 chunks of 8 k's, chunk kc stored at slot (kc ^ (row&15)).
__global__ __launch_bounds__(256) void wprep(const float* __restrict__ W,
                                             uint4* __restrict__ WTg) {
    const int cid = blockIdx.x * 256 + threadIdx.x;   // 2560 chunks
    if (cid >= 2560) return;
    const int row = cid >> 4;
    const int csn = cid & 15;
    const int kc = csn ^ (row & 15);
    unsigned p[4];
    #pragma unroll
    for (int e = 0; e < 4; ++e) {
        const float a = W[(kc * 8 + e * 2) * 160 + row];
        const float b = W[(kc * 8 + e * 2 + 1) * 160 + row];
        p[e] = (unsigned)f2bf(a) | ((unsigned)f2bf(b) << 16);
    }
    WTg[cid] = make_uint4(p[0], p[1], p[2], p[3]);
}

// u_hat via bf16 MFMA (A = W rows, B = u cols). Barrier-free main loop:
// u held in registers (32 pos/wave), W fragments direct from global (L1/L2),
// C stored fragment-native. Only LDS: 2 KB col-sum fold (1 barrier pair).
__global__ __launch_bounds__(256) void gemm_uhat(const float* __restrict__ u,
                                                 const uint4* __restrict__ WTg,
                                                 uint2* __restrict__ uf2,
                                                 float* __restrict__ partial) {
    const int b = blockIdx.x;
    const int blk = blockIdx.y;            // 32 blocks per b, 128 pos each
    const int t = threadIdx.x;
    const int l = t & 63;
    const int wv = __builtin_amdgcn_readfirstlane(t >> 6);

    const float4* u4g = (const float4*)u;
    const short8* wt8g = (const short8*)WTg;

    // ---- load this wave's 32 positions of u into registers (bf16 packed),
    //      accumulating f32 column sums ----
    float cs[4][8];
    #pragma unroll
    for (int kk = 0; kk < 4; ++kk)
        #pragma unroll
        for (int e = 0; e < 8; ++e) cs[kk][e] = 0.f;

    short8 ubf[2][4];
    #pragma unroll
    for (int mt = 0; mt < 2; ++mt) {
        const size_t row = (size_t)b * NPOS + blk * 128 + mt * 64 + wv * 16 + (l & 15);
        #pragma unroll
        for (int kk = 0; kk < 4; ++kk) {
            const float4 x0 = u4g[row * 32 + kk * 8 + (l >> 4) * 2];
            const float4 x1 = u4g[row * 32 + kk * 8 + (l >> 4) * 2 + 1];
            cs[kk][0] += x0.x; cs[kk][1] += x0.y; cs[kk][2] += x0.z; cs[kk][3] += x0.w;
            cs[kk][4] += x1.x; cs[kk][5] += x1.y; cs[kk][6] += x1.z; cs[kk][7] += x1.w;
            short8 a;
            a[0] = (short)f2bf(x0.x); a[1] = (short)f2bf(x0.y);
            a[2] = (short)f2bf(x0.z); a[3] = (short)f2bf(x0.w);
            a[4] = (short)f2bf(x1.x); a[5] = (short)f2bf(x1.y);
            a[6] = (short)f2bf(x1.z); a[7] = (short)f2bf(x1.w);
            ubf[mt][kk] = a;
        }
    }

    // ---- n-outer: 4 W-frag loads (global, L1-hot) + 8 MFMA + 2 stores ----
    #pragma unroll 2
    for (int n = 0; n < 10; ++n) {
        short8 wf[4];
        #pragma unroll
        for (int kk = 0; kk < 4; ++kk)
            wf[kk] = wt8g[(n * 16 + (l & 15)) * 16 + ((kk * 4 + (l >> 4)) ^ (l & 15))];
        #pragma unroll
        for (int mt = 0; mt < 2; ++mt) {
            floatx4 a = {0.f, 0.f, 0.f, 0.f};
            #pragma unroll
            for (int kk = 0; kk < 4; ++kk)
                a = __builtin_amdgcn_mfma_f32_16x16x32_bf16(wf[kk], ubf[mt][kk], a, 0, 0, 0);
            uint2 pk;
            pk.x = (unsigned)f2bf(a[0]) | ((unsigned)f2bf(a[1]) << 16);
            pk.y = (unsigned)f2bf(a[2]) | ((unsigned)f2bf(a[3]) << 16);
            const size_t cell = ((size_t)(b * 64 + blk * 2 + mt) * 4 + wv) * 10;
            uf2[(cell + n) * 64 + l] = pk;
        }
    }

    // ---- fold col-sums: reduce 16 pos-lanes; 4 waves via 2 KB LDS ----
    __shared__ float csbuf[4][128];
    #pragma unroll
    for (int kk = 0; kk < 4; ++kk)
        #pragma unroll
        for (int e = 0; e < 8; ++e) {
            float v = cs[kk][e];
            v += __shfl_xor(v, 1); v += __shfl_xor(v, 2);
            v += __shfl_xor(v, 4); v += __shfl_xor(v, 8);
            cs[kk][e] = v;
        }
    if ((l & 15) == 0) {
        #pragma unroll
        for (int kk = 0; kk < 4; ++kk)
            #pragma unroll
            for (int e = 0; e < 8; ++e)
                csbuf[wv][kk * 32 + (l >> 4) * 8 + e] = cs[kk][e];
    }
    __syncthreads();
    if (t < 128)
        partial[(size_t)(b * 32 + blk) * 128 + t] =
            csbuf[0][t] + csbuf[1][t] + csbuf[2][t] + csbuf[3][t];
}

// v1 from col-sum partials: s1 = 0.1 * (sum_i u) @ W -> squash -> vbuf.
__global__ __launch_bounds__(128) void small0(const float* __restrict__ partial,
                                              const float* __restrict__ W,
                                              float* __restrict__ vbuf) {
    const int b = blockIdx.x / NCAP;
    const int n = blockIdx.x % NCAP;
    const int t = threadIdx.x;
    __shared__ float xv[DIN];
    float a = 0.f;
    #pragma unroll 8
    for (int c = 0; c < 32; ++c)
        a += partial[(size_t)(b * 32 + c) * DIN + t];
    xv[t] = a;
    __syncthreads();
    if (t < DCAP) {
        float sv = 0.f;
        for (int d = 0; d < DIN; ++d)
            sv = fmaf(xv[d], W[d * 160 + n * DCAP + t], sv);
        sv *= 0.1f;
        float nq = sv * sv;
        #pragma unroll
        for (int mm = 8; mm >= 1; mm >>= 1) nq += __shfl_xor(nq, mm, 16);
        nq += 1e-7f;
        vbuf[(size_t)(b * NCAP + n) * DCAP + t] = sv * sqrtf(nq) / (1.0f + nq);
    }
}

// Routing: restage fragment-native uf -> [64 pos][160] LDS, then R10-style
// p1 (lane=pos, wave=d-quarter) + p2 (t<160 owns (n,d)). Block = 64 pos.
__global__ __launch_bounds__(256) void route_uf(const uint2* __restrict__ uf2,
                                                const float* __restrict__ vbuf,
                                                float* __restrict__ pws) {
    const int b = blockIdx.x;
    const int g = blockIdx.y;              // 64 groups of 64 positions
    const int t = threadIdx.x;
    const int l = t & 63;
    const int w = __builtin_amdgcn_readfirstlane(t >> 6);

    __shared__ __align__(16) short tls[64 * 168];   // 21504 B ([pos][160] +pad)
    __shared__ float lgp[4][64][10];                // 10240 B
    __shared__ float csm[64][10];                   // 2560 B

    // ---- restage: wave w copies its wv=w cell (10 x 512 B, coalesced) ----
    const size_t base = (size_t)(b * 64 + g) * 2560 + (size_t)w * 640;
    const int pos = w * 16 + (l & 15);
    const int d0 = (l >> 4) * 4;
    #pragma unroll
    for (int n = 0; n < 10; ++n) {
        const uint2 q = uf2[base + n * 64 + l];
        *(uint2*)&tls[pos * 168 + n * 16 + d0] = q;
    }
    __syncthreads();

    // ---- p1: lane = pos, wave = d-quarter; partial dots -> lgp ----
    #pragma unroll
    for (int n = 0; n < 10; ++n) {
        const uint2 uu = *(const uint2*)&tls[l * 168 + n * 16 + w * 4];
        const float4 vq = *(const float4*)&vbuf[(size_t)(b * 10 + n) * 16 + w * 4];
        lgp[w][l][n] = bflo(uu.x) * vq.x + bfhi(uu.x) * vq.y +
                       bflo(uu.y) * vq.z + bfhi(uu.y) * vq.w;
    }
    __syncthreads();

    // ---- fold + softmax (redundant per wave); wave 0 publishes c ----
    float c[10];
    float m = -1e30f;
    #pragma unroll
    for (int n = 0; n < 10; ++n) {
        c[n] = lgp[0][l][n] + lgp[1][l][n] + lgp[2][l][n] + lgp[3][l][n];
        m = fmaxf(m, c[n]);
    }
    float ssum = 0.f;
    #pragma unroll
    for (int n = 0; n < 10; ++n) { c[n] = __expf(c[n] - m); ssum += c[n]; }
    const float inv = 1.0f / ssum;
    if (w == 0) {
        #pragma unroll
        for (int n = 0; n < 10; ++n) csm[l][n] = c[n] * inv;
    }
    __syncthreads();

    // ---- p2: thread t<160 owns (n,d), sums 64 positions ----
    if (t < 160) {
        const int n = t >> 4;
        float acc = 0.f;
        #pragma unroll 8
        for (int p = 0; p < 64; ++p)
            acc = fmaf(csm[p][n], bf2f((unsigned short)tls[p * 168 + t]), acc);
        pws[(size_t)(b * 64 + g) * 160 + t] = acc;
    }
}

// Fold 64 block-partials -> s -> squash -> v (dst = vbuf or out).
__global__ __launch_bounds__(256) void smallv(const float* __restrict__ pws,
                                              float* __restrict__ dst) {
    const int b = blockIdx.x;
    const int t = threadIdx.x;
    if (t >= 160) return;
    float a = 0.f;
    #pragma unroll 8
    for (int c = 0; c < 64; ++c)
        a += pws[(size_t)(b * 64 + c) * 160 + t];
    float nq = a * a;
    #pragma unroll
    for (int mm = 8; mm >= 1; mm >>= 1) nq += __shfl_xor(nq, mm, 16);
    nq += 1e-7f;
    dst[(size_t)b * 160 + t] = a * sqrtf(nq) / (1.0f + nq);
}

// ===========================================================================
// FALLBACK PATH (R7, verified): f32 routing against w = W @ v.
// ===========================================================================

__global__ __launch_bounds__(256) void caps_sum(const float* __restrict__ u,
                                                float* __restrict__ partial) {
    const int b = blockIdx.x;
    const int chunk = blockIdx.y;
    const int t = threadIdx.x;
    const int v4 = t & 31;
    const int prow = t >> 5;
    const float4* up = (const float4*)u;
    const size_t posbase = (size_t)b * NPOS + chunk * 256;
    float4 acc = make_float4(0.f, 0.f, 0.f, 0.f);
    #pragma unroll 8
    for (int j = 0; j < 32; ++j) {
        float4 x = up[(posbase + prow + j * 8) * 32 + v4];
        acc.x += x.x; acc.y += x.y; acc.z += x.z; acc.w += x.w;
    }
    __shared__ float4 red[8][32];
    red[prow][v4] = acc;
    __syncthreads();
    if (t < 32) {
        float4 s = red[0][t];
        #pragma unroll
        for (int r = 1; r < 8; ++r) {
            s.x += red[r][t].x; s.y += red[r][t].y;
            s.z += red[r][t].z; s.w += red[r][t].w;
        }
        ((float4*)partial)[((size_t)b * 16 + chunk) * 32 + t] = s;
    }
}

template <int MODE>
__global__ __launch_bounds__(128) void caps_small(const float* __restrict__ src,
                                                  const float* __restrict__ W,
                                                  float* __restrict__ dst) {
    const int b = blockIdx.x / NCAP;
    const int n = blockIdx.x % NCAP;
    const int t = threadIdx.x;
    __shared__ float xv[DIN];
    __shared__ float vv[DCAP];
    float a = 0.f;
    if (MODE == 0) {
        #pragma unroll 4
        for (int c = 0; c < 16; ++c) a += src[(size_t)(b * 16 + c) * DIN + t];
    } else {
        #pragma unroll 4
        for (int c = 0; c < 16; ++c) a += src[((size_t)(b * 16 + c) * NCAP + n) * DIN + t];
    }
    xv[t] = a;
    __syncthreads();
    if (t < DCAP) {
        float sv = 0.f;
        for (int d = 0; d < DIN; ++d) sv = fmaf(xv[d], W[d * 160 + n * DCAP + t], sv);
        if (MODE == 0) sv *= 0.1f;
        float nq = sv * sv;
        #pragma unroll
        for (int mm = 8; mm >= 1; mm >>= 1) nq += __shfl_xor(nq, mm, 16);
        nq += 1e-7f;
        const float v = sv * sqrtf(nq) / (1.0f + nq);
        if (MODE == 2) dst[(size_t)(b * NCAP + n) * DCAP + t] = v;
        else vv[t] = v;
    }
    if (MODE != 2) {
        __syncthreads();
        float wd = 0.f;
        #pragma unroll
        for (int dd = 0; dd < DCAP; ++dd)
            wd = fmaf(W[t * 160 + n * DCAP + dd], vv[dd], wd);
        dst[(size_t)(b * NCAP + n) * DIN + t] = wd;
    }
}

__global__ __launch_bounds__(256, 3) void caps_route(const float* __restrict__ u,
                                                     const float* __restrict__ wsrc,
                                                     float* __restrict__ pdst) {
    const int b = blockIdx.x;
    const int tile = blockIdx.y;
    const int t = threadIdx.x;
    const int lane = t & 63;
    const int wv = __builtin_amdgcn_readfirstlane(t >> 6);
    __shared__ float4 tl4[64 * 32];
    __shared__ float lgp[4][64][11];
    float* tlf = (float*)tl4;
    const float4* wq4 = (const float4*)(wsrc + (size_t)b * (NCAP * DIN));
    float acc0[NCAP], acc1[NCAP];
    #pragma unroll
    for (int n = 0; n < NCAP; ++n) { acc0[n] = 0.f; acc1[n] = 0.f; }
    for (int s = 0; s < 4; ++s) {
        __syncthreads();
        const float4* src4 = (const float4*)u + ((size_t)b * NPOS + tile * 256 + s * 64) * 32;
        #pragma unroll
        for (int i = 0; i < 8; ++i) {
            const int q = t + i * 256;
            const int r = q >> 5, c = q & 31;
            tl4[r * 32 + (c ^ (r & 7))] = src4[q];
        }
        __syncthreads();
        float lg[NCAP];
        #pragma unroll
        for (int n = 0; n < NCAP; ++n) lg[n] = 0.f;
        #pragma unroll
        for (int j = 0; j < 8; ++j) {
            const float4 u4 = tl4[lane * 32 + wv * 8 + (j ^ (lane & 7))];
            #pragma unroll
            for (int n = 0; n < NCAP; ++n) {
                const float4 w4 = wq4[n * 32 + wv * 8 + j];
                lg[n] = fmaf(u4.x, w4.x, fmaf(u4.y, w4.y,
                        fmaf(u4.z, w4.z, fmaf(u4.w, w4.w, lg[n]))));
            }
        }
        #pragma unroll
        for (int n = 0; n < NCAP; ++n) lgp[wv][lane][n] = lg[n];
        __syncthreads();
        float c[NCAP];
        float m = -1e30f;
        #pragma unroll
        for (int n = 0; n < NCAP; ++n) {
            c[n] = lgp[0][lane][n] + lgp[1][lane][n] + lgp[2][lane][n] + lgp[3][lane][n];
            m = fmaxf(m, c[n]);
        }
        float ssum = 0.f;
        #pragma unroll
        for (int n = 0; n < NCAP; ++n) { c[n] = __expf(c[n] - m); ssum += c[n]; }
        const float inv = 1.0f / ssum;
        #pragma unroll
        for (int n = 0; n < NCAP; ++n) c[n] *= inv;
        const int col0 = lane >> 2, word = lane & 3;
        #pragma unroll
        for (int i = 0; i < 16; ++i) {
            const int p = wv * 16 + i;
            const int ca = col0 ^ (p & 7);
            const float u0 = tlf[(p * 32 + ca) * 4 + word];
            const float u1 = tlf[(p * 32 + ca + 16) * 4 + word];
            #pragma unroll
            for (int n = 0; n < NCAP; ++n) {
                const float cp = __int_as_float(
                    __builtin_amdgcn_readlane(__float_as_int(c[n]), p));
                acc0[n] = fmaf(cp, u0, acc0[n]);
                acc1[n] = fmaf(cp, u1, acc1[n]);
            }
        }
    }
    __syncthreads();
    float* red = tlf;
    #pragma unroll
    for (int n = 0; n < NCAP; ++n) {
        red[(wv * NCAP + n) * DIN + lane]      = acc0[n];
        red[(wv * NCAP + n) * DIN + lane + 64] = acc1[n];
    }
    __syncthreads();
    float* pb = pdst + (size_t)(b * 16 + tile) * (NCAP * DIN);
    for (int k = t; k < NCAP * DIN; k += 256)
        pb[k] = red[k] + red[1280 + k] + red[2560 + k] + red[3840 + k];
}

extern "C" void kernel_launch(void* const* d_in, const int* in_sizes, int n_in,
                              void* d_out, int out_size, void* d_ws, size_t ws_size,
                              hipStream_t stream) {
    const float* u = (const float*)d_in[0];   // [64][4096][128]
    const float* W = (const float*)d_in[1];   // [128][160]
    float* out = (float*)d_out;               // [64][10][16]
    char* wsb = (char*)d_ws;

    if (ws_size >= 86679552ull) {
        float* partial = (float*)wsb;                       // 1 MB (region A)
        float* pws     = (float*)wsb;                       // 2.62 MB (region A, after small0)
        float* vbuf    = (float*)(wsb + 2621440);           // 40 KB
        uint4* WTg     = (uint4*)(wsb + 2662400);           // 40 KB
        uint2* uf2     = (uint2*)(wsb + 2703360);           // 83.9 MB

        wprep<<<10, 256, 0, stream>>>(W, WTg);
        gemm_uhat<<<dim3(NB, 32), 256, 0, stream>>>(u, WTg, uf2, partial);
        small0<<<NB * NCAP, 128, 0, stream>>>(partial, W, vbuf);       // v1
        route_uf<<<dim3(NB, 64), 256, 0, stream>>>(uf2, vbuf, pws);    // iter 2
        smallv<<<NB, 256, 0, stream>>>(pws, vbuf);                     // v2
        route_uf<<<dim3(NB, 64), 256, 0, stream>>>(uf2, vbuf, pws);    // iter 3
        smallv<<<NB, 256, 0, stream>>>(pws, out);                      // v3 -> out
    } else {
        float* partial = (float*)wsb;
        float* wbuf    = (float*)wsb + 131072;
        float* pws32   = (float*)wsb + 212992;
        caps_sum<<<dim3(NB, 16), 256, 0, stream>>>(u, partial);
        caps_small<0><<<NB * NCAP, 128, 0, stream>>>(partial, W, wbuf);
        caps_route<<<dim3(NB, 16), 256, 0, stream>>>(u, wbuf, pws32);
        caps_small<1><<<NB * NCAP, 128, 0, stream>>>(pws32, W, wbuf);
        caps_route<<<dim3(NB, 16), 256, 0, stream>>>(u, wbuf, pws32);
        caps_small<2><<<NB * NCAP, 128, 0, stream>>>(pws32, W, out);
    }
}

// Round 16
// 107.965 us; speedup vs baseline: 1.2338x; 1.0694x over previous
//
#include <hip/hip_runtime.h>
#include <hip/hip_bf16.h>
#include <math.h>

#define NCAP 10
#define DCAP 16
#define DIN  128
#define NPOS 4096
#define NB   64

typedef short short8 __attribute__((ext_vector_type(8)));
typedef float floatx4 __attribute__((ext_vector_type(4)));

__device__ inline float bflo(unsigned v) { return __uint_as_float(v << 16); }
__device__ inline float bfhi(unsigned v) { return __uint_as_float(v & 0xFFFF0000u); }
__device__ inline unsigned short f2bf(float f) {           // round-to-nearest-even
    unsigned u = __float_as_uint(f);
    return (unsigned short)((u + 0x7FFFu + ((u >> 16) & 1u)) >> 16);
}
__device__ inline float bf2f(unsigned short h) { return __uint_as_float(((unsigned)h) << 16); }

// ===========================================================================
// BIG PATH (ws >= 86,679,552 B; uses 86,589,440)
//   regionA : @0, 2,621,440 B — first 1 MB: col-sum partial [64][32][128] f32
//             (consumed by small0); then route partials pws [64][64][160] f32
//   vbuf    : @2,621,440 (40,960 B)  f32 [64][10][16]
//   WTg     : @2,662,400 (40,960 B)  bf16 swizzled W [160 rows][16 chunks]
//   uf      : @2,703,360 (83,886,080 B) fragment-native u_hat (bf16 pairs)
//             uint2 index: (((b*64 + g)*4 + wv)*10 + n)*64 + l  where
//             lane l: pos = g*64 + wv*16 + (l&15), d = (l>>4)*4 + {0..3}
// ===========================================================================

// One-time: pre-swizzle W (f32 [128][160]) -> WTg rows=out-col(n*16+d),
// 16 chunks of 8 k's, chunk kc stored at slot (kc ^ (row&15)).
__global__ __launch_bounds__(256) void wprep(const float* __restrict__ W,
                                             uint4* __restrict__ WTg) {
    const int cid = blockIdx.x * 256 + threadIdx.x;   // 2560 chunks
    if (cid >= 2560) return;
    const int row = cid >> 4;
    const int csn = cid & 15;
    const int kc = csn ^ (row & 15);
    unsigned p[4];
    #pragma unroll
    for (int e = 0; e < 4; ++e) {
        const float a = W[(kc * 8 + e * 2) * 160 + row];
        const float b = W[(kc * 8 + e * 2 + 1) * 160 + row];
        p[e] = (unsigned)f2bf(a) | ((unsigned)f2bf(b) << 16);
    }
    WTg[cid] = make_uint4(p[0], p[1], p[2], p[3]);
}

// u_hat via bf16 MFMA (A = W rows, B = u cols).
// R15 change (single-variable vs R14): u is read DENSE-coalesced, converted
// in-register, transposed through a WAVE-PRIVATE XOR-swizzled LDS buffer
// (no barriers), then B-frags ds_read_b128 into registers. W-frags from
// global WTg (unchanged), C stored fragment-native (unchanged).
__global__ __launch_bounds__(256) void gemm_uhat(const float* __restrict__ u,
                                                 const uint4* __restrict__ WTg,
                                                 uint2* __restrict__ uf2,
                                                 float* __restrict__ partial) {
    const int b = blockIdx.x;
    const int blk = blockIdx.y;            // 32 blocks per b, 128 pos each
    const int t = threadIdx.x;
    const int l = t & 63;
    const int wv = __builtin_amdgcn_readfirstlane(t >> 6);

    __shared__ __align__(16) char ust[4][8192];   // wave-private u staging
    __shared__ float csbuf[4][128];               // col-sum fold

    const float4* u4g = (const float4*)u;
    const short8* wt8g = (const short8*)WTg;
    char* myst = ust[wv];

    // ---- stage this wave's 32 positions: dense reads + cvt + swz LDS ----
    const int col4 = l & 31;               // float4 column (k-chunk kcs, half hh)
    const int par  = l >> 5;               // row parity
    const int kcs  = col4 >> 1;
    const int hh   = col4 & 1;
    float cs4[4] = {0.f, 0.f, 0.f, 0.f};

    #pragma unroll
    for (int r = 0; r < 2; ++r) {
        #pragma unroll
        for (int i = 0; i < 8; ++i) {
            const int pl = r * 16 + i * 2 + par;   // pos_local 0..31
            const size_t grow = (size_t)b * NPOS + blk * 128 + wv * 32 + pl;
            const float4 x = u4g[grow * 32 + col4];
            cs4[0] += x.x; cs4[1] += x.y; cs4[2] += x.z; cs4[3] += x.w;
            uint2 pk;
            pk.x = (unsigned)f2bf(x.x) | ((unsigned)f2bf(x.y) << 16);
            pk.y = (unsigned)f2bf(x.z) | ((unsigned)f2bf(x.w) << 16);
            *(uint2*)&myst[pl * 256 + ((kcs ^ (pl & 15)) << 4) + hh * 8] = pk;
        }
    }

    // ---- B-frags from wave-private LDS (2-way max, free) ----
    short8 bfr[2][4];
    #pragma unroll
    for (int mt = 0; mt < 2; ++mt)
        #pragma unroll
        for (int kk = 0; kk < 4; ++kk)
            bfr[mt][kk] = *(const short8*)&myst[(mt * 16 + (l & 15)) * 256 +
                              (((kk * 4 + (l >> 4)) ^ (l & 15)) << 4)];

    // ---- n-loop: 4 W-frag global loads + 8 MFMA + 2 frag-native stores ----
    const int sub = 2 * wv;                // (w*2 + mt) base
    #pragma unroll 2
    for (int n = 0; n < 10; ++n) {
        short8 wf[4];
        #pragma unroll
        for (int kk = 0; kk < 4; ++kk)
            wf[kk] = wt8g[(n * 16 + (l & 15)) * 16 + ((kk * 4 + (l >> 4)) ^ (l & 15))];
        #pragma unroll
        for (int mt = 0; mt < 2; ++mt) {
            floatx4 a = {0.f, 0.f, 0.f, 0.f};
            #pragma unroll
            for (int kk = 0; kk < 4; ++kk)
                a = __builtin_amdgcn_mfma_f32_16x16x32_bf16(wf[kk], bfr[mt][kk], a, 0, 0, 0);
            uint2 pk;
            pk.x = (unsigned)f2bf(a[0]) | ((unsigned)f2bf(a[1]) << 16);
            pk.y = (unsigned)f2bf(a[2]) | ((unsigned)f2bf(a[3]) << 16);
            const int sm = sub + mt;       // 0..7 within block
            const size_t cell = ((size_t)(b * 64 + blk * 2 + (sm >> 2)) * 4 + (sm & 3)) * 10;
            uf2[(cell + n) * 64 + l] = pk;
        }
    }

    // ---- fold col-sums: parity shfl + 4-wave LDS fold (single barrier) ----
    #pragma unroll
    for (int e = 0; e < 4; ++e) cs4[e] += __shfl_xor(cs4[e], 32);
    if (l < 32)
        *(float4*)&csbuf[wv][l * 4] = make_float4(cs4[0], cs4[1], cs4[2], cs4[3]);
    __syncthreads();
    if (t < 128)
        partial[(size_t)(b * 32 + blk) * 128 + t] =
            csbuf[0][t] + csbuf[1][t] + csbuf[2][t] + csbuf[3][t];
}

// v1 from col-sum partials: s1 = 0.1 * (sum_i u) @ W -> squash -> vbuf.
__global__ __launch_bounds__(128) void small0(const float* __restrict__ partial,
                                              const float* __restrict__ W,
                                              float* __restrict__ vbuf) {
    const int b = blockIdx.x / NCAP;
    const int n = blockIdx.x % NCAP;
    const int t = threadIdx.x;
    __shared__ float xv[DIN];
    float a = 0.f;
    #pragma unroll 8
    for (int c = 0; c < 32; ++c)
        a += partial[(size_t)(b * 32 + c) * DIN + t];
    xv[t] = a;
    __syncthreads();
    if (t < DCAP) {
        float sv = 0.f;
        for (int d = 0; d < DIN; ++d)
            sv = fmaf(xv[d], W[d * 160 + n * DCAP + t], sv);
        sv *= 0.1f;
        float nq = sv * sv;
        #pragma unroll
        for (int mm = 8; mm >= 1; mm >>= 1) nq += __shfl_xor(nq, mm, 16);
        nq += 1e-7f;
        vbuf[(size_t)(b * NCAP + n) * DCAP + t] = sv * sqrtf(nq) / (1.0f + nq);
    }
}

// Routing: restage fragment-native uf -> [64 pos][160] LDS, then R10-style
// p1 (lane=pos, wave=d-quarter) + p2 (t<160 owns (n,d)). Block = 64 pos.
__global__ __launch_bounds__(256) void route_uf(const uint2* __restrict__ uf2,
                                                const float* __restrict__ vbuf,
                                                float* __restrict__ pws) {
    const int b = blockIdx.x;
    const int g = blockIdx.y;              // 64 groups of 64 positions
    const int t = threadIdx.x;
    const int l = t & 63;
    const int w = __builtin_amdgcn_readfirstlane(t >> 6);

    __shared__ __align__(16) short tls[64 * 168];   // 21504 B ([pos][160] +pad)
    __shared__ float lgp[4][64][10];                // 10240 B
    __shared__ float csm[64][10];                   // 2560 B

    // ---- restage: wave w copies its wv=w cell (10 x 512 B, coalesced) ----
    const size_t base = (size_t)(b * 64 + g) * 2560 + (size_t)w * 640;
    const int pos = w * 16 + (l & 15);
    const int d0 = (l >> 4) * 4;
    #pragma unroll
    for (int n = 0; n < 10; ++n) {
        const uint2 q = uf2[base + n * 64 + l];
        *(uint2*)&tls[pos * 168 + n * 16 + d0] = q;
    }
    __syncthreads();

    // ---- p1: lane = pos, wave = d-quarter; partial dots -> lgp ----
    #pragma unroll
    for (int n = 0; n < 10; ++n) {
        const uint2 uu = *(const uint2*)&tls[l * 168 + n * 16 + w * 4];
        const float4 vq = *(const float4*)&vbuf[(size_t)(b * 10 + n) * 16 + w * 4];
        lgp[w][l][n] = bflo(uu.x) * vq.x + bfhi(uu.x) * vq.y +
                       bflo(uu.y) * vq.z + bfhi(uu.y) * vq.w;
    }
    __syncthreads();

    // ---- fold + softmax (redundant per wave); wave 0 publishes c ----
    float c[10];
    float m = -1e30f;
    #pragma unroll
    for (int n = 0; n < 10; ++n) {
        c[n] = lgp[0][l][n] + lgp[1][l][n] + lgp[2][l][n] + lgp[3][l][n];
        m = fmaxf(m, c[n]);
    }
    float ssum = 0.f;
    #pragma unroll
    for (int n = 0; n < 10; ++n) { c[n] = __expf(c[n] - m); ssum += c[n]; }
    const float inv = 1.0f / ssum;
    if (w == 0) {
        #pragma unroll
        for (int n = 0; n < 10; ++n) csm[l][n] = c[n] * inv;
    }
    __syncthreads();

    // ---- p2: thread t<160 owns (n,d), sums 64 positions ----
    if (t < 160) {
        const int n = t >> 4;
        float acc = 0.f;
        #pragma unroll 8
        for (int p = 0; p < 64; ++p)
            acc = fmaf(csm[p][n], bf2f((unsigned short)tls[p * 168 + t]), acc);
        pws[(size_t)(b * 64 + g) * 160 + t] = acc;
    }
}

// Fold 64 block-partials -> s -> squash -> v (dst = vbuf or out).
__global__ __launch_bounds__(256) void smallv(const float* __restrict__ pws,
                                              float* __restrict__ dst) {
    const int b = blockIdx.x;
    const int t = threadIdx.x;
    if (t >= 160) return;
    float a = 0.f;
    #pragma unroll 8
    for (int c = 0; c < 64; ++c)
        a += pws[(size_t)(b * 64 + c) * 160 + t];
    float nq = a * a;
    #pragma unroll
    for (int mm = 8; mm >= 1; mm >>= 1) nq += __shfl_xor(nq, mm, 16);
    nq += 1e-7f;
    dst[(size_t)b * 160 + t] = a * sqrtf(nq) / (1.0f + nq);
}

// ===========================================================================
// FALLBACK PATH (R7, verified): f32 routing against w = W @ v.
// ===========================================================================

__global__ __launch_bounds__(256) void caps_sum(const float* __restrict__ u,
                                                float* __restrict__ partial) {
    const int b = blockIdx.x;
    const int chunk = blockIdx.y;
    const int t = threadIdx.x;
    const int v4 = t & 31;
    const int prow = t >> 5;
    const float4* up = (const float4*)u;
    const size_t posbase = (size_t)b * NPOS + chunk * 256;
    float4 acc = make_float4(0.f, 0.f, 0.f, 0.f);
    #pragma unroll 8
    for (int j = 0; j < 32; ++j) {
        float4 x = up[(posbase + prow + j * 8) * 32 + v4];
        acc.x += x.x; acc.y += x.y; acc.z += x.z; acc.w += x.w;
    }
    __shared__ float4 red[8][32];
    red[prow][v4] = acc;
    __syncthreads();
    if (t < 32) {
        float4 s = red[0][t];
        #pragma unroll
        for (int r = 1; r < 8; ++r) {
            s.x += red[r][t].x; s.y += red[r][t].y;
            s.z += red[r][t].z; s.w += red[r][t].w;
        }
        ((float4*)partial)[((size_t)b * 16 + chunk) * 32 + t] = s;
    }
}

template <int MODE>
__global__ __launch_bounds__(128) void caps_small(const float* __restrict__ src,
                                                  const float* __restrict__ W,
                                                  float* __restrict__ dst) {
    const int b = blockIdx.x / NCAP;
    const int n = blockIdx.x % NCAP;
    const int t = threadIdx.x;
    __shared__ float xv[DIN];
    __shared__ float vv[DCAP];
    float a = 0.f;
    if (MODE == 0) {
        #pragma unroll 4
        for (int c = 0; c < 16; ++c) a += src[(size_t)(b * 16 + c) * DIN + t];
    } else {
        #pragma unroll 4
        for (int c = 0; c < 16; ++c) a += src[((size_t)(b * 16 + c) * NCAP + n) * DIN + t];
    }
    xv[t] = a;
    __syncthreads();
    if (t < DCAP) {
        float sv = 0.f;
        for (int d = 0; d < DIN; ++d) sv = fmaf(xv[d], W[d * 160 + n * DCAP + t], sv);
        if (MODE == 0) sv *= 0.1f;
        float nq = sv * sv;
        #pragma unroll
        for (int mm = 8; mm >= 1; mm >>= 1) nq += __shfl_xor(nq, mm, 16);
        nq += 1e-7f;
        const float v = sv * sqrtf(nq) / (1.0f + nq);
        if (MODE == 2) dst[(size_t)(b * NCAP + n) * DCAP + t] = v;
        else vv[t] = v;
    }
    if (MODE != 2) {
        __syncthreads();
        float wd = 0.f;
        #pragma unroll
        for (int dd = 0; dd < DCAP; ++dd)
            wd = fmaf(W[t * 160 + n * DCAP + dd], vv[dd], wd);
        dst[(size_t)(b * NCAP + n) * DIN + t] = wd;
    }
}

__global__ __launch_bounds__(256, 3) void caps_route(const float* __restrict__ u,
                                                     const float* __restrict__ wsrc,
                                                     float* __restrict__ pdst) {
    const int b = blockIdx.x;
    const int tile = blockIdx.y;
    const int t = threadIdx.x;
    const int lane = t & 63;
    const int wv = __builtin_amdgcn_readfirstlane(t >> 6);
    __shared__ float4 tl4[64 * 32];
    __shared__ float lgp[4][64][11];
    float* tlf = (float*)tl4;
    const float4* wq4 = (const float4*)(wsrc + (size_t)b * (NCAP * DIN));
    float acc0[NCAP], acc1[NCAP];
    #pragma unroll
    for (int n = 0; n < NCAP; ++n) { acc0[n] = 0.f; acc1[n] = 0.f; }
    for (int s = 0; s < 4; ++s) {
        __syncthreads();
        const float4* src4 = (const float4*)u + ((size_t)b * NPOS + tile * 256 + s * 64) * 32;
        #pragma unroll
        for (int i = 0; i < 8; ++i) {
            const int q = t + i * 256;
            const int r = q >> 5, c = q & 31;
            tl4[r * 32 + (c ^ (r & 7))] = src4[q];
        }
        __syncthreads();
        float lg[NCAP];
        #pragma unroll
        for (int n = 0; n < NCAP; ++n) lg[n] = 0.f;
        #pragma unroll
        for (int j = 0; j < 8; ++j) {
            const float4 u4 = tl4[lane * 32 + wv * 8 + (j ^ (lane & 7))];
            #pragma unroll
            for (int n = 0; n < NCAP; ++n) {
                const float4 w4 = wq4[n * 32 + wv * 8 + j];
                lg[n] = fmaf(u4.x, w4.x, fmaf(u4.y, w4.y,
                        fmaf(u4.z, w4.z, fmaf(u4.w, w4.w, lg[n]))));
            }
        }
        #pragma unroll
        for (int n = 0; n < NCAP; ++n) lgp[wv][lane][n] = lg[n];
        __syncthreads();
        float c[NCAP];
        float m = -1e30f;
        #pragma unroll
        for (int n = 0; n < NCAP; ++n) {
            c[n] = lgp[0][lane][n] + lgp[1][lane][n] + lgp[2][lane][n] + lgp[3][lane][n];
            m = fmaxf(m, c[n]);
        }
        float ssum = 0.f;
        #pragma unroll
        for (int n = 0; n < NCAP; ++n) { c[n] = __expf(c[n] - m); ssum += c[n]; }
        const float inv = 1.0f / ssum;
        #pragma unroll
        for (int n = 0; n < NCAP; ++n) c[n] *= inv;
        const int col0 = lane >> 2, word = lane & 3;
        #pragma unroll
        for (int i = 0; i < 16; ++i) {
            const int p = wv * 16 + i;
            const int ca = col0 ^ (p & 7);
            const float u0 = tlf[(p * 32 + ca) * 4 + word];
            const float u1 = tlf[(p * 32 + ca + 16) * 4 + word];
            #pragma unroll
            for (int n = 0; n < NCAP; ++n) {
                const float cp = __int_as_float(
                    __builtin_amdgcn_readlane(__float_as_int(c[n]), p));
                acc0[n] = fmaf(cp, u0, acc0[n]);
                acc1[n] = fmaf(cp, u1, acc1[n]);
            }
        }
    }
    __syncthreads();
    float* red = tlf;
    #pragma unroll
    for (int n = 0; n < NCAP; ++n) {
        red[(wv * NCAP + n) * DIN + lane]      = acc0[n];
        red[(wv * NCAP + n) * DIN + lane + 64] = acc1[n];
    }
    __syncthreads();
    float* pb = pdst + (size_t)(b * 16 + tile) * (NCAP * DIN);
    for (int k = t; k < NCAP * DIN; k += 256)
        pb[k] = red[k] + red[1280 + k] + red[2560 + k] + red[3840 + k];
}

extern "C" void kernel_launch(void* const* d_in, const int* in_sizes, int n_in,
                              void* d_out, int out_size, void* d_ws, size_t ws_size,
                              hipStream_t stream) {
    const float* u = (const float*)d_in[0];   // [64][4096][128]
    const float* W = (const float*)d_in[1];   // [128][160]
    float* out = (float*)d_out;               // [64][10][16]
    char* wsb = (char*)d_ws;

    if (ws_size >= 86679552ull) {
        float* partial = (float*)wsb;                       // 1 MB (region A)
        float* pws     = (float*)wsb;                       // 2.62 MB (region A, after small0)
        float* vbuf    = (float*)(wsb + 2621440);           // 40 KB
        uint4* WTg     = (uint4*)(wsb + 2662400);           // 40 KB
        uint2* uf2     = (uint2*)(wsb + 2703360);           // 83.9 MB

        wprep<<<10, 256, 0, stream>>>(W, WTg);
        gemm_uhat<<<dim3(NB, 32), 256, 0, stream>>>(u, WTg, uf2, partial);
        small0<<<NB * NCAP, 128, 0, stream>>>(partial, W, vbuf);       // v1
        route_uf<<<dim3(NB, 64), 256, 0, stream>>>(uf2, vbuf, pws);    // iter 2
        smallv<<<NB, 256, 0, stream>>>(pws, vbuf);                     // v2
        route_uf<<<dim3(NB, 64), 256, 0, stream>>>(uf2, vbuf, pws);    // iter 3
        smallv<<<NB, 256, 0, stream>>>(pws, out);                      // v3 -> out
    } else {
        float* partial = (float*)wsb;
        float* wbuf    = (float*)wsb + 131072;
        float* pws32   = (float*)wsb + 212992;
        caps_sum<<<dim3(NB, 16), 256, 0, stream>>>(u, partial);
        caps_small<0><<<NB * NCAP, 128, 0, stream>>>(partial, W, wbuf);
        caps_route<<<dim3(NB, 16), 256, 0, stream>>>(u, wbuf, pws32);
        caps_small<1><<<NB * NCAP, 128, 0, stream>>>(pws32, W, wbuf);
        caps_route<<<dim3(NB, 16), 256, 0, stream>>>(u, wbuf, pws32);
        caps_small<2><<<NB * NCAP, 128, 0, stream>>>(pws32, W, out);
    }
}